// Round 1
// baseline (557.910 us; speedup 1.0000x reference)
//
#include <hip/hip_runtime.h>
#include <stdint.h>

typedef unsigned short u16;
typedef unsigned int   u32;
typedef __attribute__((ext_vector_type(8))) short short8;   // 8 bf16 = 4 VGPRs (MFMA A/B frag)
typedef __attribute__((ext_vector_type(4))) float f32x4;    // MFMA C/D frag

#define TPB 256
#define FPB 64            // frames per block (64 | 4000? no — blocks may straddle batches; handled by batch guard)
#define NB 257            // nbands
#define LF 513            // FIR length
#define FS 80             // framesize
#define NCH 9             // K chunks of 32 (K = 288: k=1..256 in chunks 0..7, chunk 8 = H0 rank-1 term)
#define MT_TOTAL 33       // tap tiles of 16 -> 528 taps (513 real + 15 zero)
#define HROW 296          // Hlds row stride in ushorts (288 data + 8 pad; 592B -> 2-way banks)
#define FROW 536          // fir row stride in ushorts: 8 zero-prefix + 528 taps (1072B -> 2-way banks)
#define TAB_ELEMS (MT_TOTAL*NCH*64*8)   // 152064 bf16 = 304128 B in ws

__device__ __forceinline__ u32 f2bf(float f){          // fp32 -> bf16 bits (RNE)
  u32 u = __float_as_uint(f);
  return (u + 0x7fffu + ((u >> 16) & 1u)) >> 16;
}
#define BF2LO(u) __uint_as_float((u) << 16)
#define BF2HI(u) __uint_as_float((u) & 0xffff0000u)

// ---------------------------------------------------------------------------
// Table: T stored in exact MFMA A-fragment order: elem((mt*9+c)*64+lane, j) =
//   A[tap = mt*16 + (lane&15)][kslot = c*32 + (lane>>4)*8 + j]
//   kslot<256: coeff of H[kslot+1] = (2/513)*hann[tap]*cos(2pi*(kslot+1)*(tap-256)/513)
//   kslot==256: coeff of H[0]     = hann[tap]/513          (rank-1 term folded into GEMM)
//   tap>=513 or kslot>256: 0
// ---------------------------------------------------------------------------
__global__ void build_table(u16* __restrict__ tab){
  int id = blockIdx.x * blockDim.x + threadIdx.x;
  if (id >= TAB_ELEMS) return;
  int j    = id & 7;
  int lane = (id >> 3) & 63;
  int cc   = (id >> 9) % NCH;
  int mt   = (id >> 9) / NCH;
  int tap  = mt * 16 + (lane & 15);
  int kslot= cc * 32 + (lane >> 4) * 8 + j;
  float val = 0.f;
  if (tap < LF){
    float hann = 0.5f - 0.5f * cosf(6.28318530717958647f * (float)tap / 513.f);
    if (kslot < 256){
      int k  = kslot + 1;
      int rr = (k * (tap + 257)) % 513;            // (tap-256) mod 513 == tap+257 mod 513
      val = (2.f / 513.f) * hann * cosf((float)rr * (6.28318530717958647f / 513.f));
    } else if (kslot == 256){
      val = hann * (1.f / 513.f);
    }
  }
  tab[id] = (u16)f2bf(val);
}

// ---------------------------------------------------------------------------
// Fused: stage H/noise -> MFMA GEMM (fir = T * H^T) -> fir to LDS -> conv+OLA
// ---------------------------------------------------------------------------
__launch_bounds__(TPB, 2)
__global__ void fused(const float* __restrict__ Hg, const float* __restrict__ noiseg,
                      const u16* __restrict__ tab, float* __restrict__ out, int outTotal){
  __shared__ u16 uSh[FPB * FROW];        // GEMM phase: aliases Hlds[64][296]; conv phase: fir[64][536]
  __shared__ u16 noiseSh[FPB * FS];      // bf16 noise [64][80]

  const int tid  = threadIdx.x;
  const int lane = tid & 63;
  const int w    = tid >> 6;
  const int ln15 = lane & 15;
  const int q    = lane >> 4;
  const int blk  = blockIdx.x;
  const int f0   = blk * FPB;

  u16* Hlds = uSh;                       // [64][HROW]: kk 0..255 = H[k+1], kk 256 = H[0], 257..287 = 0

  // ---- stage H (fp32 -> bf16 pairs) ----
  #pragma unroll
  for (int e = 0; e < 32; ++e){
    int id = tid + TPB * e;              // 8192 pair tasks over 64 rows x 128 pairs
    int r = id >> 7, p = id & 127;
    const float* gp = Hg + (size_t)(f0 + r) * NB + 1 + 2 * p;
    u32 lo = f2bf(gp[0]), hi = f2bf(gp[1]);
    *(u32*)&Hlds[r * HROW + 2 * p] = lo | (hi << 16);
  }
  if (tid < 64){                         // kk 256 <- H0 (hi half = 0 covers kk 257)
    *(u32*)&Hlds[tid * HROW + 256] = f2bf(Hg[(size_t)(f0 + tid) * NB]);
  }
  #pragma unroll
  for (int e = 0; e < 5; ++e){           // zero kk 258..295 (19 u32 per row)
    int id = tid + TPB * e;
    if (id < 64 * 19){
      int r = id / 19, c2 = id % 19;
      *(u32*)&Hlds[r * HROW + 258 + 2 * c2] = 0u;
    }
  }
  // ---- stage noise: u*2-1, bf16 pairs ----
  #pragma unroll
  for (int e = 0; e < 10; ++e){
    int id = tid + TPB * e;              // 2560 pair tasks over 64 rows x 40 pairs
    int r = id / 40, c2 = id % 40;
    float2 v = *(const float2*)(noiseg + (size_t)(f0 + r) * FS + 2 * c2);
    u32 lo = f2bf(v.x * 2.f - 1.f), hi = f2bf(v.y * 2.f - 1.f);
    *(u32*)&noiseSh[r * FS + 2 * c2] = lo | (hi << 16);
  }
  __syncthreads();

  // ---- GEMM: fir[tap][frame] = sum_k T[tap][k] * Hlds[frame][k] ----
  const int mtBegin = (w == 0) ? 0 : (9 + 8 * (w - 1));   // {0,9,17,25}
  const int mtCount = (w == 0) ? 9 : 8;                   // 33 tap-tiles total
  f32x4 acc[9][4];
  #pragma unroll
  for (int a = 0; a < 9; ++a)
    #pragma unroll
    for (int b = 0; b < 4; ++b) acc[a][b] = (f32x4){0.f, 0.f, 0.f, 0.f};

  const short8* tab8 = (const short8*)tab;
  for (int c = 0; c < NCH; ++c){
    short8 bfrag[4];
    #pragma unroll
    for (int nt = 0; nt < 4; ++nt)       // B-frag: lane ln15 = frame, 8 contiguous k
      bfrag[nt] = *(const short8*)&Hlds[(nt * 16 + ln15) * HROW + c * 32 + q * 8];
    #pragma unroll
    for (int mt = 0; mt < 9; ++mt){
      if (mt < mtCount){
        short8 afrag = tab8[((mtBegin + mt) * NCH + c) * 64 + lane];  // L2-cached, frag-ordered
        #pragma unroll
        for (int nt = 0; nt < 4; ++nt)
          acc[mt][nt] = __builtin_amdgcn_mfma_f32_16x16x32_bf16(afrag, bfrag[nt], acc[mt][nt], 0, 0, 0);
      }
    }
  }
  __syncthreads();                       // all waves done reading Hlds; reuse region as fir

  // ---- epilogue: C/D (col=lane&15=frame, row=quad*4+reg=tap) -> fir LDS bf16 ----
  u16* fir = uSh;                        // [64][FROW], data at +8
  #pragma unroll
  for (int mt = 0; mt < 9; ++mt){
    if (mt < mtCount){
      int tap0 = (mtBegin + mt) * 16 + q * 4;
      #pragma unroll
      for (int nt = 0; nt < 4; ++nt){
        int frame = nt * 16 + ln15;
        f32x4 v = acc[mt][nt];
        uint2 pk;
        pk.x = f2bf(v.x) | (f2bf(v.y) << 16);
        pk.y = f2bf(v.z) | (f2bf(v.w) << 16);
        *(uint2*)&fir[frame * FROW + 8 + tap0] = pk;
      }
    }
  }
  if (tid < 256){                        // 8-ushort zero prefix per row (64 rows x 4 u32)
    int r = tid >> 2, s = tid & 3;
    ((u32*)&fir[r * FROW])[s] = 0u;
  }
  __syncthreads();

  // ---- conv + OLA: thread gathers 8 outputs; sliding 12-float fir window ----
  for (int task = tid; task < 704; task += TPB){
    int s0 = blk * (FPB * FS) + task * 8;          // flat output index (= b*320000 + tau*80 + j)
    if (s0 >= outTotal) continue;
    int qb = s0 / 320000;                           // batch row (8 samples never straddle)
    int fA = max(f0, qb * 4000);
    int fB = min(f0 + FPB, qb * 4000 + 4000);       // exclusive: frames of this block in batch qb
    int fLo = max(fA, (s0 >= 512) ? (s0 - 512) / 80 : 0);
    int fHi = min(fB - 1, (s0 + 7) / 80);           // inclusive
    float ac[8];
    #pragma unroll
    for (int r = 0; r < 8; ++r) ac[r] = 0.f;

    for (int f = fLo; f <= fHi; ++f){
      int frel = f - f0;
      int j0 = s0 - 80 * f;                         // in [0, 584], j0 % 8 == 0
      const u16* frow = uSh + frel * FROW + 8;      // tap 0
      const u16* nrow = noiseSh + frel * FS;
      int gLo = (j0 > 512) ? ((j0 - 512) >> 2) : 0;
      int gHi = min(19, (j0 >> 2) + 1);
      float F[12];                                  // F[k] = fir[j0-4g-4+k]
      int x = j0 - 4 * gLo;
      uint2 q1 = *(const uint2*)(frow + x);
      uint2 q2 = *(const uint2*)(frow + x + 4);
      F[4] = BF2LO(q1.x); F[5] = BF2HI(q1.x); F[6]  = BF2LO(q1.y); F[7]  = BF2HI(q1.y);
      F[8] = BF2LO(q2.x); F[9] = BF2HI(q2.x); F[10] = BF2LO(q2.y); F[11] = BF2HI(q2.y);
      for (int g = gLo; g <= gHi; ++g){
        uint2 q0 = *(const uint2*)(frow + (j0 - 4 * g - 4));   // hits zero-prefix at edges
        F[0] = BF2LO(q0.x); F[1] = BF2HI(q0.x); F[2] = BF2LO(q0.y); F[3] = BF2HI(q0.y);
        uint2 nq = *(const uint2*)(nrow + 4 * g);
        float n0 = BF2LO(nq.x), n1 = BF2HI(nq.x), n2 = BF2LO(nq.y), n3 = BF2HI(nq.y);
        #pragma unroll
        for (int r = 0; r < 8; ++r){
          ac[r] = fmaf(n0, F[4 + r], ac[r]);
          ac[r] = fmaf(n1, F[3 + r], ac[r]);
          ac[r] = fmaf(n2, F[2 + r], ac[r]);
          ac[r] = fmaf(n3, F[1 + r], ac[r]);
        }
        F[8] = F[4]; F[9] = F[5]; F[10] = F[6]; F[11] = F[7];
        F[4] = F[0]; F[5] = F[1]; F[6]  = F[2]; F[7]  = F[3];
      }
    }
    // interior tasks (rel samples [512,5120)) are single-owner: plain vector store.
    // boundary fringes shared with neighbor blocks: atomicAdd (out pre-zeroed).
    if (task >= 64 && task < 640){
      float4 v0 = make_float4(ac[0], ac[1], ac[2], ac[3]);
      float4 v1 = make_float4(ac[4], ac[5], ac[6], ac[7]);
      *(float4*)&out[s0]     = v0;
      *(float4*)&out[s0 + 4] = v1;
    } else if (fLo <= fHi){
      #pragma unroll
      for (int r = 0; r < 8; ++r) atomicAdd(&out[s0 + r], ac[r]);
    }
  }
}

extern "C" void kernel_launch(void* const* d_in, const int* in_sizes, int n_in,
                              void* d_out, int out_size, void* d_ws, size_t ws_size,
                              hipStream_t stream){
  const float* Hg     = (const float*)d_in[0];   // [32,4000,257] fp32
  const float* noiseg = (const float*)d_in[1];   // [32,4000,80]  fp32
  float* out = (float*)d_out;                    // [32,320000]   fp32
  u16* tab = (u16*)d_ws;                         // 304128 B

  hipMemsetAsync(d_out, 0, (size_t)out_size * sizeof(float), stream);
  build_table<<<TAB_ELEMS / TPB, TPB, 0, stream>>>(tab);
  fused<<<(32 * 4000) / FPB, TPB, 0, stream>>>(Hg, noiseg, tab, out, out_size);
}

// Round 2
// 528.634 us; speedup vs baseline: 1.0554x; 1.0554x over previous
//
#include <hip/hip_runtime.h>
#include <stdint.h>

typedef unsigned short u16;
typedef unsigned int   u32;
typedef __attribute__((ext_vector_type(8))) short short8;   // 8 bf16 = 4 VGPRs (MFMA A/B frag)
typedef __attribute__((ext_vector_type(4))) float f32x4;    // MFMA C/D frag

#define TPB 256
#define FPB 64            // frames per block
#define NB 257            // nbands
#define LF 513            // FIR length
#define FS 80             // framesize
#define NCH 9             // K chunks of 32 (K = 288: k=1..256 in chunks 0..7, chunk 8 = H0 rank-1 term)
#define MT_TOTAL 33       // tap tiles of 16 -> 528 taps (513 real + 15 zero)
#define HROW 296          // Hlds row stride in u16 (592B: 16B-aligned rows for b128 b-frags, conflict-free)
#define FROW 540          // fir row stride in u16: 8 zero-prefix + 528 taps + 4 pad. 1080B rows: 8B-aligned,
                          // bank-stride 14 -> 4 accesses/bank on b64 = LDS floor (was 536 -> stride 12, gcd 4)
#define NROW 84           // noise row stride in u16 (168B rows: 8B-aligned, bank-stride 10 -> b64 floor)
#define TAB_ELEMS (MT_TOTAL*NCH*64*8)   // 152064 bf16 = 304128 B in ws

__device__ __forceinline__ u32 f2bf(float f){          // fp32 -> bf16 bits (RNE)
  u32 u = __float_as_uint(f);
  return (u + 0x7fffu + ((u >> 16) & 1u)) >> 16;
}
#define BF2LO(u) __uint_as_float((u) << 16)
#define BF2HI(u) __uint_as_float((u) & 0xffff0000u)

// ---------------------------------------------------------------------------
// Table: T in exact MFMA A-fragment order (see round-1 comment). Unchanged.
// ---------------------------------------------------------------------------
__global__ void build_table(u16* __restrict__ tab){
  int id = blockIdx.x * blockDim.x + threadIdx.x;
  if (id >= TAB_ELEMS) return;
  int j    = id & 7;
  int lane = (id >> 3) & 63;
  int cc   = (id >> 9) % NCH;
  int mt   = (id >> 9) / NCH;
  int tap  = mt * 16 + (lane & 15);
  int kslot= cc * 32 + (lane >> 4) * 8 + j;
  float val = 0.f;
  if (tap < LF){
    float hann = 0.5f - 0.5f * cosf(6.28318530717958647f * (float)tap / 513.f);
    if (kslot < 256){
      int k  = kslot + 1;
      int rr = (k * (tap + 257)) % 513;
      val = (2.f / 513.f) * hann * cosf((float)rr * (6.28318530717958647f / 513.f));
    } else if (kslot == 256){
      val = hann * (1.f / 513.f);
    }
  }
  tab[id] = (u16)f2bf(val);
}

// Inner conv for one (output-octet, frame) pair. j0 = s0 - 80*f (multiple of 8).
// frow points at tap 0 (8 zero halfs live below it). Uniform path passes scalar j0.
__device__ __forceinline__ void convFrame(const u16* frow, const u16* nrow, int j0, float ac[8]){
  int gLo = (j0 > 512) ? ((j0 - 512) >> 2) : 0;
  int gHi = min(19, (j0 >> 2) + 1);
  float F[12];                                  // F[k] = fir[j0-4g-4+k]
  int x = j0 - 4 * gLo;
  uint2 q1 = *(const uint2*)(frow + x);
  uint2 q2 = *(const uint2*)(frow + x + 4);
  F[4] = BF2LO(q1.x); F[5] = BF2HI(q1.x); F[6]  = BF2LO(q1.y); F[7]  = BF2HI(q1.y);
  F[8] = BF2LO(q2.x); F[9] = BF2HI(q2.x); F[10] = BF2LO(q2.y); F[11] = BF2HI(q2.y);
  for (int g = gLo; g <= gHi; ++g){
    uint2 q0 = *(const uint2*)(frow + (j0 - 4 * g - 4));   // hits zero-prefix at edges
    F[0] = BF2LO(q0.x); F[1] = BF2HI(q0.x); F[2] = BF2LO(q0.y); F[3] = BF2HI(q0.y);
    uint2 nq = *(const uint2*)(nrow + 4 * g);
    float n0 = BF2LO(nq.x), n1 = BF2HI(nq.x), n2 = BF2LO(nq.y), n3 = BF2HI(nq.y);
    #pragma unroll
    for (int r = 0; r < 8; ++r){
      ac[r] = fmaf(n0, F[4 + r], ac[r]);
      ac[r] = fmaf(n1, F[3 + r], ac[r]);
      ac[r] = fmaf(n2, F[2 + r], ac[r]);
      ac[r] = fmaf(n3, F[1 + r], ac[r]);
    }
    F[8] = F[4]; F[9] = F[5]; F[10] = F[6]; F[11] = F[7];
    F[4] = F[0]; F[5] = F[1]; F[6]  = F[2]; F[7]  = F[3];
  }
}

// ---------------------------------------------------------------------------
// Fused: stage H/noise -> MFMA GEMM (fir = T * H^T) -> fir to LDS -> conv+OLA
// ---------------------------------------------------------------------------
__launch_bounds__(TPB, 2)
__global__ void fused(const float* __restrict__ Hg, const float* __restrict__ noiseg,
                      const u16* __restrict__ tab, float* __restrict__ out, int outTotal){
  __shared__ u16 uSh[FPB * FROW];        // GEMM phase: aliases Hlds[64][296]; conv phase: fir[64][540]
  __shared__ u16 noiseSh[FPB * NROW];    // bf16 noise [64][84]

  const int tid  = threadIdx.x;
  const int lane = tid & 63;
  const int w    = tid >> 6;
  const int ln15 = lane & 15;
  const int q    = lane >> 4;
  const int blk  = blockIdx.x;
  const int f0   = blk * FPB;

  u16* Hlds = uSh;                       // [64][HROW]: kk 0..255 = H[k+1], kk 256 = H[0], 257..287 = 0

  // ---- stage H (fp32 -> bf16 pairs) ----
  #pragma unroll
  for (int e = 0; e < 32; ++e){
    int id = tid + TPB * e;              // 8192 pair tasks over 64 rows x 128 pairs
    int r = id >> 7, p = id & 127;
    const float* gp = Hg + (size_t)(f0 + r) * NB + 1 + 2 * p;
    u32 lo = f2bf(gp[0]), hi = f2bf(gp[1]);
    *(u32*)&Hlds[r * HROW + 2 * p] = lo | (hi << 16);
  }
  if (tid < 64){                         // kk 256 <- H0 (hi half = 0 covers kk 257)
    *(u32*)&Hlds[tid * HROW + 256] = f2bf(Hg[(size_t)(f0 + tid) * NB]);
  }
  #pragma unroll
  for (int e = 0; e < 5; ++e){           // zero kk 258..295 (19 u32 per row)
    int id = tid + TPB * e;
    if (id < 64 * 19){
      int r = id / 19, c2 = id % 19;
      *(u32*)&Hlds[r * HROW + 258 + 2 * c2] = 0u;
    }
  }
  // ---- stage noise: u*2-1, bf16 pairs ----
  #pragma unroll
  for (int e = 0; e < 10; ++e){
    int id = tid + TPB * e;              // 2560 pair tasks over 64 rows x 40 pairs
    int r = id / 40, c2 = id % 40;
    float2 v = *(const float2*)(noiseg + (size_t)(f0 + r) * FS + 2 * c2);
    u32 lo = f2bf(v.x * 2.f - 1.f), hi = f2bf(v.y * 2.f - 1.f);
    *(u32*)&noiseSh[r * NROW + 2 * c2] = lo | (hi << 16);
  }
  __syncthreads();

  // ---- GEMM: fir[tap][frame] = sum_k T[tap][k] * Hlds[frame][k] ----
  const int mtBegin = (w == 0) ? 0 : (9 + 8 * (w - 1));   // {0,9,17,25}
  const int mtCount = (w == 0) ? 9 : 8;                   // 33 tap-tiles total
  f32x4 acc[9][4];
  #pragma unroll
  for (int a = 0; a < 9; ++a)
    #pragma unroll
    for (int b = 0; b < 4; ++b) acc[a][b] = (f32x4){0.f, 0.f, 0.f, 0.f};

  const short8* tab8 = (const short8*)tab;
  for (int c = 0; c < NCH; ++c){
    short8 bfrag[4];
    #pragma unroll
    for (int nt = 0; nt < 4; ++nt)       // B-frag: lane ln15 = frame, 8 contiguous k
      bfrag[nt] = *(const short8*)&Hlds[(nt * 16 + ln15) * HROW + c * 32 + q * 8];
    #pragma unroll
    for (int mt = 0; mt < 9; ++mt){
      if (mt < mtCount){
        short8 afrag = tab8[((mtBegin + mt) * NCH + c) * 64 + lane];  // L2-cached, frag-ordered
        #pragma unroll
        for (int nt = 0; nt < 4; ++nt)
          acc[mt][nt] = __builtin_amdgcn_mfma_f32_16x16x32_bf16(afrag, bfrag[nt], acc[mt][nt], 0, 0, 0);
      }
    }
  }
  __syncthreads();                       // all waves done reading Hlds; reuse region as fir

  // ---- epilogue: C/D (col=lane&15=frame, row=quad*4+reg=tap) -> fir LDS bf16 ----
  u16* fir = uSh;                        // [64][FROW], data at +8
  #pragma unroll
  for (int mt = 0; mt < 9; ++mt){
    if (mt < mtCount){
      int tap0 = (mtBegin + mt) * 16 + q * 4;
      #pragma unroll
      for (int nt = 0; nt < 4; ++nt){
        int frame = nt * 16 + ln15;
        f32x4 v = acc[mt][nt];
        uint2 pk;
        pk.x = f2bf(v.x) | (f2bf(v.y) << 16);
        pk.y = f2bf(v.z) | (f2bf(v.w) << 16);
        *(uint2*)&fir[frame * FROW + 8 + tap0] = pk;
      }
    }
  }
  if (tid < 256){                        // 8-ushort zero prefix per row (64 rows x 4 u32)
    int r = tid >> 2, s = tid & 3;
    ((u32*)&fir[r * FROW])[s] = 0u;
  }
  __syncthreads();

  // ---- conv + OLA, wave-uniform remap ----
  // Lane L takes task = t0 + 10*L (t0 = 0..9): all lanes share s0 mod 80, so for
  // frame offset d (frel = L - d), j0 = 8*t0 + 80*d is WAVE-SCALAR -> uniform
  // frame/g loops; only a per-lane frel-validity mask remains.
  const int base = blk * (FPB * FS);
  for (int t0 = w; t0 < 10; t0 += 4){
    const int task = t0 + 10 * lane;                // 0..639
    const int s0 = base + task * 8;
    const int qb = s0 / 320000;                      // batch row of these 8 samples
    const int rLo = max(0, qb * 4000 - f0);          // valid frel range [rLo, rHi)
    const int rHi = min(FPB, qb * 4000 + 4000 - f0);
    float ac[8];
    #pragma unroll
    for (int r = 0; r < 8; ++r) ac[r] = 0.f;

    const int dMax = (t0 >= 4) ? 6 : 7;              // j0 = 8*t0+560 > 591 for t0>=4
    for (int d = 0; d <= dMax; ++d){
      const int frel = lane - d;
      const int j0 = 8 * t0 + 80 * d;                // wave-scalar
      if (frel >= rLo && frel < rHi){
        convFrame(uSh + frel * FROW + 8, noiseSh + frel * NROW, j0, ac);
      }
    }
    if (task >= 64){                                 // interior: single-owner vector store
      *(float4*)&out[s0]     = make_float4(ac[0], ac[1], ac[2], ac[3]);
      *(float4*)&out[s0 + 4] = make_float4(ac[4], ac[5], ac[6], ac[7]);
    } else {                                         // left fringe shared with prev block
      #pragma unroll
      for (int r = 0; r < 8; ++r) atomicAdd(&out[s0 + r], ac[r]);
    }
  }

  // ---- tail tasks 640..703 (samples [5120, 5632) rel): small, keep gather form ----
  if (w == 3){
    const int task = 640 + lane;
    const int s0 = base + task * 8;
    if (s0 < outTotal){
      const int qb = s0 / 320000;
      const int fA = max(f0, qb * 4000);
      const int fB = min(f0 + FPB, qb * 4000 + 4000);
      const int fLo = max(fA, (s0 - 512) / 80);
      const int fHi = min(fB - 1, (s0 + 7) / 80);
      float ac[8];
      #pragma unroll
      for (int r = 0; r < 8; ++r) ac[r] = 0.f;
      for (int f = fLo; f <= fHi; ++f){
        convFrame(uSh + (f - f0) * FROW + 8, noiseSh + (f - f0) * NROW, s0 - 80 * f, ac);
      }
      if (fLo <= fHi){
        #pragma unroll
        for (int r = 0; r < 8; ++r) atomicAdd(&out[s0 + r], ac[r]);
      }
    }
  }
}

extern "C" void kernel_launch(void* const* d_in, const int* in_sizes, int n_in,
                              void* d_out, int out_size, void* d_ws, size_t ws_size,
                              hipStream_t stream){
  const float* Hg     = (const float*)d_in[0];   // [32,4000,257] fp32
  const float* noiseg = (const float*)d_in[1];   // [32,4000,80]  fp32
  float* out = (float*)d_out;                    // [32,320000]   fp32
  u16* tab = (u16*)d_ws;                         // 304128 B

  hipMemsetAsync(d_out, 0, (size_t)out_size * sizeof(float), stream);
  build_table<<<TAB_ELEMS / TPB, TPB, 0, stream>>>(tab);
  fused<<<(32 * 4000) / FPB, TPB, 0, stream>>>(Hg, noiseg, tab, out, out_size);
}